// Round 9
// baseline (152.678 us; speedup 1.0000x reference)
//
#include <hip/hip_runtime.h>

#define B_ 4
#define T_ 4096
#define C_ 1024
#define H_ 64

typedef _Float16 half8  __attribute__((ext_vector_type(8)));
typedef _Float16 half4_ __attribute__((ext_vector_type(4)));
typedef float    floatx4 __attribute__((ext_vector_type(4)));

#define MFMA16(a, b, c) __builtin_amdgcn_mfma_f32_16x16x32_f16(a, b, c, 0, 0, 0)

__device__ __forceinline__ void glds16(const float* g, float* l) {
    __builtin_amdgcn_global_load_lds(
        (const __attribute__((address_space(1))) unsigned int*)g,
        (__attribute__((address_space(3))) unsigned int*)l, 16, 0, 0);
}

// ---------------------------------------------------------------------------
// Kernel 1: pack W into MFMA-fragment order (lane-contiguous A-frags).
// ---------------------------------------------------------------------------
__global__ __launch_bounds__(256) void pack_w_kn(
    const float* __restrict__ Wq, const float* __restrict__ Wk,
    const float* __restrict__ Wv, _Float16* __restrict__ Wt2)
{
    const int idx  = blockIdx.x * 256 + threadIdx.x;  // 0 .. 196607
    const int mt   = idx >> 14;
    const int j    = (idx >> 10) & 15;
    const int f    = (idx >> 9) & 1;
    const int lane = (idx >> 3) & 63;
    const int jj   = idx & 7;
    const int q = lane >> 4, c = lane & 15;
    const int k  = j * 64 + f * 32 + q * 8 + jj;
    const int hp = mt * 16 + c;                       // 0..191
    const float* W = (hp < 64) ? Wq : (hp < 128) ? Wk : Wv;
    Wt2[idx] = (_Float16)W[k * H_ + (hp & 63)];
}

// ---------------------------------------------------------------------------
// Kernel 2: fused QKV projection.  x staged fp32 via global_load_lds w=16
// (fire-and-forget, dbuf, no VGPR round-trip).  XOR column swizzle
// (chunk ^= row&7) on the glds SOURCE keeps frag reads 2-way-bank-free.
// B-frags: 4x ds_read_b128 fp32 + cvt_pk -> f16.  A-frags: packed Wt2, 1-KB
// coalesced L2 loads.  Epilogue: Q/K/V fragment-packed (round-8 layouts).
// ---------------------------------------------------------------------------
__global__ __launch_bounds__(512) void qkv_kn(
    const float* __restrict__ x, const _Float16* __restrict__ Wt2,
    _Float16* __restrict__ Qpk, _Float16* __restrict__ Kpk,
    _Float16* __restrict__ Vpk)
{
    __shared__ float xs[2][32][64];                   // 16 KB, NO pad (glds)
    const int tid  = threadIdx.x;
    const int lane = tid & 63, w = tid >> 6;          // w 0..7
    const int q    = lane >> 4, c = lane & 15;
    const int nt   = w & 1;                           // n-half (16 rows)
    const int mg   = w >> 1;                          // m-group (3 m-tiles)
    const int row0 = blockIdx.x * 32;

    // glds source: thread fills LDS slot (grow, pch); fetches logical chunk
    // lch = pch ^ (grow&7) so reads can un-swizzle conflict-free.
    const int grow = tid >> 4;                        // 0..31
    const int pch  = tid & 15;
    const int lch  = pch ^ (grow & 7);
    const float* xsrc = x + (size_t)(row0 + grow) * C_ + lch * 4;

    floatx4 acc[3];
    #pragma unroll
    for (int i = 0; i < 3; ++i) acc[i] = floatx4{0.f, 0.f, 0.f, 0.f};

    glds16(xsrc, &xs[0][w * 4][0]);                   // stage j=0

    for (int j = 0; j < 16; ++j) {
        __syncthreads();                              // drains glds (vmcnt 0)
        if (j < 15)
            glds16(xsrc + (j + 1) * 64, &xs[(j + 1) & 1][w * 4][0]);

        // B-frags: row = x-row, un-swizzled chunks, fp32 -> f16
        const float* rowp = &xs[j & 1][nt * 16 + c][0];
        const int e = c & 7;
        const float4 f0 = *(const float4*)(rowp + ((2 * q)     ^ e) * 4);
        const float4 f1 = *(const float4*)(rowp + ((2 * q + 1) ^ e) * 4);
        const float4 f2 = *(const float4*)(rowp + ((8 + 2 * q) ^ e) * 4);
        const float4 f3 = *(const float4*)(rowp + ((9 + 2 * q) ^ e) * 4);
        half8 b0, b1;
        b0[0] = (_Float16)f0.x; b0[1] = (_Float16)f0.y;
        b0[2] = (_Float16)f0.z; b0[3] = (_Float16)f0.w;
        b0[4] = (_Float16)f1.x; b0[5] = (_Float16)f1.y;
        b0[6] = (_Float16)f1.z; b0[7] = (_Float16)f1.w;
        b1[0] = (_Float16)f2.x; b1[1] = (_Float16)f2.y;
        b1[2] = (_Float16)f2.z; b1[3] = (_Float16)f2.w;
        b1[4] = (_Float16)f3.x; b1[5] = (_Float16)f3.y;
        b1[6] = (_Float16)f3.z; b1[7] = (_Float16)f3.w;

        // A-frags: 6 lane-contiguous 1-KB loads from L2-hot packed Wt2
        half8 a[6];
        #pragma unroll
        for (int i = 0; i < 3; ++i) {
            const size_t fb = ((size_t)((mg * 3 + i) * 16 + j) * 2) * 512 + lane * 8;
            a[i * 2]     = *(const half8*)(Wt2 + fb);
            a[i * 2 + 1] = *(const half8*)(Wt2 + fb + 512);
        }
        #pragma unroll
        for (int i = 0; i < 3; ++i) {
            acc[i] = MFMA16(a[i * 2],     b0, acc[i]);
            acc[i] = MFMA16(a[i * 2 + 1], b1, acc[i]);
        }
    }

    // epilogue (round-8): lane col = x-row row0+nt*16+c; rows h'=gi*16+q*4+r
    const int row = row0 + nt * 16 + c;
    const int b = row >> 12, t4 = row & (T_ - 1);
    const int kt = t4 >> 6;
    const size_t tbase = ((size_t)b * 64 + kt) * 4096;
    const int mtk = (t4 >> 4) & 3;
    const int kk  = t4 & 63;

    #pragma unroll
    for (int i = 0; i < 3; ++i) {
        const int gi = mg * 3 + i;                    // m-tile 0..11
        if (gi < 4) {                                 // Q fragment-packed
            half4_ v;
            #pragma unroll
            for (int r = 0; r < 4; ++r) v[r] = (_Float16)acc[i][r];
            const int qa = (gi * 2 + (q >> 1)) & 3;
            *(half4_*)(Qpk + ((size_t)b * 256 + (t4 >> 4)) * 1024
                       + ((size_t)((gi >> 1) * 64 + qa * 16 + c)) * 8
                       + (q & 1) * 4) = v;
        } else if (gi < 8) {                          // K fragment-packed
            half4_ v;
            #pragma unroll
            for (int r = 0; r < 4; ++r) v[r] = (_Float16)acc[i][r];
            const int e2 = gi - 4;
            const int f  = e2 >> 1;
            const int qa = (e2 * 2 + (q >> 1)) & 3;
            *(half4_*)(Kpk + tbase + ((size_t)(mtk * 2 + f) * 64 + qa * 16 + c) * 8
                       + (q & 1) * 4) = v;
        } else {                                      // V fragment-packed
            const int mtv = gi - 8;
            const int qa = (kk >> 3) & 3, fv = kk >> 5, jv = kk & 7;
            #pragma unroll
            for (int r = 0; r < 4; ++r) {
                const int cv = q * 4 + r;
                Vpk[tbase + ((size_t)(mtv * 2 + fv) * 64 + qa * 16 + cv) * 8 + jv]
                    = (_Float16)acc[i][r];
            }
        }
    }
}

// ---------------------------------------------------------------------------
// Kernel 3: causal flash attention.  Block = TWO 16-row q-tiles {255-bx, bx}
// done sequentially -> uniform ~65 iters/block (no dispatch assumptions).
// 8-way in-block split-K; fragment-packed Q/K/V (lane-contiguous loads).
// K software-pipelined: after S consumes K-frags, the same regs are reloaded
// with K(kt+8) so next iteration's S never stalls on a cold load.
// ---------------------------------------------------------------------------
__global__ __launch_bounds__(512, 4) void attn_kn(
    const _Float16* __restrict__ Qpk, const _Float16* __restrict__ Kpk,
    const _Float16* __restrict__ Vpk, float* __restrict__ out)
{
    __shared__ __align__(16) char smem[36864];
    const int lane = threadIdx.x & 63;
    const int w    = threadIdx.x >> 6;                // 0..7
    const int q    = lane >> 4, c = lane & 15;
    const int b    = blockIdx.y;

    _Float16* Pw = (_Float16*)smem + w * 2304;        // wave's 2 P buffers
    float* Ol = (float*)smem;                         // [8][1088] overlay
    float* Ml = (float*)(smem + 34816);               // [8][16]
    float* Ll = (float*)(smem + 35328);               // [8][16]

    #pragma unroll 1
    for (int hf = 0; hf < 2; ++hf) {
        const int t    = hf ? (int)blockIdx.x : 255 - (int)blockIdx.x;
        const int row0 = t * 16;
        const int grow = b * T_ + row0;
        const int nk   = (t >> 2) + 1;                // 64-key tiles (last=diag)

        // Q B-frags: lane-contiguous packed load, pre-scaled (1/8)*log2(e)
        const _Float16* qp = Qpk + ((size_t)b * 256 + t) * 1024 + (size_t)lane * 8;
        half8 bq0 = *(const half8*)qp;
        half8 bq1 = *(const half8*)(qp + 512);
        const _Float16 qs = (_Float16)0.18033688f;
        bq0 *= qs; bq1 *= qs;

        floatx4 o[4];
        #pragma unroll
        for (int i = 0; i < 4; ++i) o[i] = floatx4{0.f, 0.f, 0.f, 0.f};
        float m = -3.0e38f, l = 0.f;

        half8 ka[4], kb8[4];
        if (w < nk) {                                 // preamble K(w)
            const _Float16* Kt = Kpk + ((size_t)b * 64 + w) * 4096;
            #pragma unroll
            for (int mt = 0; mt < 4; ++mt) {
                ka[mt]  = *(const half8*)(Kt + ((size_t)(mt * 2)     * 64 + lane) * 8);
                kb8[mt] = *(const half8*)(Kt + ((size_t)(mt * 2 + 1) * 64 + lane) * 8);
            }
        }

        for (int kt = w; kt < nk; kt += 8) {
            const int kb = kt * 64;

            // S^T from the already-resident K-frags
            floatx4 s[4];
            #pragma unroll
            for (int mt = 0; mt < 4; ++mt) {
                floatx4 z = floatx4{0.f, 0.f, 0.f, 0.f};
                z = MFMA16(ka[mt], bq0, z);
                s[mt] = MFMA16(kb8[mt], bq1, z);
            }

            // V(kt) loads — hidden behind softmax
            const _Float16* Vt = Vpk + ((size_t)b * 64 + kt) * 4096;
            half8 va[4], vb[4];
            #pragma unroll
            for (int mt = 0; mt < 4; ++mt) {
                va[mt] = *(const half8*)(Vt + ((size_t)(mt * 2)     * 64 + lane) * 8);
                vb[mt] = *(const half8*)(Vt + ((size_t)(mt * 2 + 1) * 64 + lane) * 8);
            }
            // K(kt+8) prefetch into the same regs — hidden behind softmax+PV
            {
                const int ktn = (kt + 8 < nk) ? kt + 8 : kt;
                const _Float16* Kt = Kpk + ((size_t)b * 64 + ktn) * 4096;
                #pragma unroll
                for (int mt = 0; mt < 4; ++mt) {
                    ka[mt]  = *(const half8*)(Kt + ((size_t)(mt * 2)     * 64 + lane) * 8);
                    kb8[mt] = *(const half8*)(Kt + ((size_t)(mt * 2 + 1) * 64 + lane) * 8);
                }
            }

            if (kt == nk - 1) {                       // causal mask (diag tile)
                #pragma unroll
                for (int mt = 0; mt < 4; ++mt)
                    #pragma unroll
                    for (int r = 0; r < 4; ++r)
                        if (kb + mt * 16 + q * 4 + r > row0 + c)
                            s[mt][r] = -3.0e38f;
            }

            // online softmax; lane holds 16 scores of ONE q-row; p in place
            float mx = s[0][0];
            #pragma unroll
            for (int mt = 0; mt < 4; ++mt)
                #pragma unroll
                for (int r = 0; r < 4; ++r) mx = fmaxf(mx, s[mt][r]);
            mx = fmaxf(mx, __shfl_xor(mx, 16, 64));
            mx = fmaxf(mx, __shfl_xor(mx, 32, 64));
            const float mn    = fmaxf(m, mx);
            const float alpha = exp2f(m - mn);
            float sl = 0.f;
            #pragma unroll
            for (int mt = 0; mt < 4; ++mt)
                #pragma unroll
                for (int r = 0; r < 4; ++r) {
                    s[mt][r] = exp2f(s[mt][r] - mn);
                    sl += s[mt][r];
                }
            sl += __shfl_xor(sl, 16, 64);
            sl += __shfl_xor(sl, 32, 64);
            l = l * alpha + sl;
            m = mn;
            #pragma unroll
            for (int mt = 0; mt < 4; ++mt)
                #pragma unroll
                for (int r = 0; r < 4; ++r) o[mt][r] *= alpha;

            // P^T -> wave-private LDS (dbuf), reload as B-frags
            _Float16* pl = Pw + ((kt >> 3) & 1) * 1152 + c * 72;
            #pragma unroll
            for (int mt = 0; mt < 4; ++mt) {
                half4_ ph;
                #pragma unroll
                for (int r = 0; r < 4; ++r) ph[r] = (_Float16)s[mt][r];
                *(half4_*)(pl + mt * 16 + q * 4) = ph;
            }
            const half8 bp0 = *(const half8*)(pl + q * 8);
            const half8 bp1 = *(const half8*)(pl + 32 + q * 8);

            // O^T += V^T · P^T
            #pragma unroll
            for (int mt = 0; mt < 4; ++mt) {
                o[mt] = MFMA16(va[mt], bp0, o[mt]);
                o[mt] = MFMA16(vb[mt], bp1, o[mt]);
            }
        }

        // ---- flash combine across the 8 waves (overlay LDS after sync) ----
        __syncthreads();
        if (q == 0) Ml[w * 16 + c] = m;
        __syncthreads();
        float M = Ml[c];
        #pragma unroll
        for (int w2 = 1; w2 < 8; ++w2) M = fmaxf(M, Ml[w2 * 16 + c]);
        const float alpha = exp2f(m - M);             // 0 for empty waves
        if (q == 0) Ll[w * 16 + c] = l * alpha;
        #pragma unroll
        for (int mt = 0; mt < 4; ++mt)
            #pragma unroll
            for (int r = 0; r < 4; ++r)
                Ol[w * 1088 + (mt * 16 + q * 4 + r) * 17 + c] = o[mt][r] * alpha;
        __syncthreads();

        float L = 0.f;
        #pragma unroll
        for (int w2 = 0; w2 < 8; ++w2) L += Ll[w2 * 16 + c];
        const float inv = 1.f / L;
        const int h0 = w * 8 + q * 2;
        float ox = 0.f, oy = 0.f;
        #pragma unroll
        for (int w2 = 0; w2 < 8; ++w2) {
            ox += Ol[w2 * 1088 + h0 * 17 + c];
            oy += Ol[w2 * 1088 + (h0 + 1) * 17 + c];
        }
        float2 st; st.x = ox * inv; st.y = oy * inv;
        *(float2*)(out + (size_t)(grow + c) * H_ + h0) = st;
        __syncthreads();                              // Ol reads done before next half's P writes
    }
}

extern "C" void kernel_launch(void* const* d_in, const int* in_sizes, int n_in,
                              void* d_out, int out_size, void* d_ws, size_t ws_size,
                              hipStream_t stream) {
    const float* x  = (const float*)d_in[0];
    const float* Wq = (const float*)d_in[1];
    const float* Wk = (const float*)d_in[2];
    const float* Wv = (const float*)d_in[3];
    float* out = (float*)d_out;

    _Float16* ws = (_Float16*)d_ws;
    _Float16* Wt2 = ws;                               //   192*1024 = 196608
    _Float16* Qpk = ws + 196608;                      // [4][256][1024]
    _Float16* Kpk = Qpk + 1048576;                    // [4][64][4096]
    _Float16* Vpk = Kpk + 1048576;                    // [4][64][4096]

    hipLaunchKernelGGL(pack_w_kn, dim3(768), dim3(256), 0, stream, Wq, Wk, Wv, Wt2);
    hipLaunchKernelGGL(qkv_kn, dim3((B_ * T_) / 32), dim3(512), 0, stream,
                       x, Wt2, Qpk, Kpk, Vpk);
    hipLaunchKernelGGL(attn_kn, dim3(T_ / 32, B_), dim3(512), 0, stream,
                       Qpk, Kpk, Vpk, out);
}